// Round 13
// baseline (4348.313 us; speedup 1.0000x reference)
//
#include <hip/hip_runtime.h>
#include <hip/hip_bf16.h>

__device__ __forceinline__ float ssp_f(float x) {
    return fmaxf(x, 0.f) + log1pf(__expf(-fabsf(x))) - 0.6931471805599453f;
}

// ---------------- float dtype sniffer ----------------------------------------
__global__ void sniff_kernel(const unsigned int* __restrict__ raw, int* __restrict__ flag)
{
    __shared__ int cnt[256];
    const int t = threadIdx.x;
    unsigned int w = raw[t];
    unsigned int e = (w >> 7) & 0xFFu;
    cnt[t] = (e >= 100u && e <= 135u) ? 1 : 0;
    __syncthreads();
    for (int s = 128; s > 0; s >>= 1) {
        if (t < s) cnt[t] += cnt[t + s];
        __syncthreads();
    }
    if (t == 0) *flag = (cnt[0] >= 160) ? 1 : 0;   // 1 = floats are bf16
}

// ---------------- int width sniffer -------------------------------------------
__global__ void sniff_int_kernel(const unsigned int* __restrict__ z, int* __restrict__ iflag)
{
    __shared__ int cnt[128];
    const int t = threadIdx.x;
    cnt[t] = (z[2 * t + 1] == 0u) ? 1 : 0;
    __syncthreads();
    for (int s = 64; s > 0; s >>= 1) {
        if (t < s) cnt[t] += cnt[t + s];
        __syncthreads();
    }
    if (t == 0) *iflag = (cnt[0] >= 126) ? 1 : 0;  // 1 = ints are int64
}

// ---------------- converts -----------------------------------------------------
__global__ __launch_bounds__(256) void convert_kernel(
    const void* __restrict__ src, float* __restrict__ dst, int n,
    const int* __restrict__ flag)
{
    int i = blockIdx.x * 256 + threadIdx.x;
    if (i >= n) return;
    if (*flag) dst[i] = __bfloat162float(((const __hip_bfloat16*)src)[i]);
    else       dst[i] = ((const float*)src)[i];
}

__global__ __launch_bounds__(256) void convert_int_kernel(
    const void* __restrict__ src, int* __restrict__ dst, int n,
    const int* __restrict__ iflag)
{
    int i = blockIdx.x * 256 + threadIdx.x;
    if (i >= n) return;
    if (*iflag) dst[i] = (int)(((const long long*)src)[i]);
    else        dst[i] = ((const int*)src)[i];
}

// ---------------- node embedding gather ---------------------------------------
__global__ __launch_bounds__(256) void embed_kernel(
    const int* __restrict__ z, const float* __restrict__ embf,
    float* __restrict__ h, int NH)
{
    int idx = blockIdx.x * 256 + threadIdx.x;
    if (idx >= NH) return;
    h[idx] = embf[z[idx >> 7] * 128 + (idx & 127)];
}

// ---------------- CSR build ----------------------------------------------------
__global__ __launch_bounds__(256) void zero_int_kernel(int* p, int n)
{
    int i = blockIdx.x * 256 + threadIdx.x;
    if (i < n) p[i] = 0;
}

__global__ __launch_bounds__(256) void hist_kernel(const int* __restrict__ col,
                                                   int* __restrict__ count, int E)
{
    int e = blockIdx.x * 256 + threadIdx.x;
    if (e < E) atomicAdd(&count[col[e]], 1);
}

// single-block exclusive scan of count[N] -> rowptr[N+1], next[N]
__global__ __launch_bounds__(256) void scan_kernel(const int* __restrict__ count,
                                                   int* __restrict__ rowptr,
                                                   int* __restrict__ next, int N)
{
    __shared__ int part[256];
    const int t = threadIdx.x;
    const int chunk = (N + 255) / 256;
    const int lo = t * chunk, hi = min(lo + chunk, N);
    int s = 0;
    for (int i = lo; i < hi; ++i) s += count[i];
    part[t] = s;
    __syncthreads();
    if (t == 0) {
        int run = 0;
        for (int i = 0; i < 256; ++i) { int v = part[i]; part[i] = run; run += v; }
        rowptr[N] = run;
    }
    __syncthreads();
    int run = part[t];
    for (int i = lo; i < hi; ++i) {
        rowptr[i] = run; next[i] = run;
        run += count[i];
    }
}

__global__ __launch_bounds__(256) void slot_kernel(const int* __restrict__ col,
                                                   int* __restrict__ next,
                                                   int* __restrict__ slot, int E)
{
    int e = blockIdx.x * 256 + threadIdx.x;
    if (e < E) slot[e] = atomicAdd(&next[col[e]], 1);
}

// ---------------- tiled node GEMM [N,128]@[128,128] ---------------------------
template<int MODE>
__global__ __launch_bounds__(256) void node_gemm_tiled(
    const float* __restrict__ in, const float* __restrict__ W,
    const float* __restrict__ bias, float* __restrict__ out, int N)
{
    __shared__ float in_s[32][128];
    const int t = threadIdx.x;
    const long n0 = (long)blockIdx.x * 32;
    for (int i = t; i < 32 * 128; i += 256) {
        long n = n0 + (i >> 7);
        in_s[i >> 7][i & 127] = (n < N) ? in[n * 128 + (i & 127)] : 0.f;
    }
    __syncthreads();
    const int j = t & 31, sub = t >> 5;
    const int c4 = j * 4, rb = sub * 4;
    float acc[4][4];
    float4 bv = make_float4(0.f, 0.f, 0.f, 0.f);
    if (MODE != 0) bv = *(const float4*)(bias + c4);
    #pragma unroll
    for (int i = 0; i < 4; ++i) { acc[i][0]=bv.x; acc[i][1]=bv.y; acc[i][2]=bv.z; acc[i][3]=bv.w; }
    #pragma unroll 4
    for (int k = 0; k < 128; ++k) {
        const float4 wv = *(const float4*)(W + k * 128 + c4);
        #pragma unroll
        for (int i = 0; i < 4; ++i) {
            const float a = in_s[rb + i][k];
            acc[i][0] += a * wv.x; acc[i][1] += a * wv.y;
            acc[i][2] += a * wv.z; acc[i][3] += a * wv.w;
        }
    }
    #pragma unroll
    for (int i = 0; i < 4; ++i) {
        long n = n0 + rb + i;
        if (n >= N) continue;
        float4 o;
        if (MODE == 1) {
            o.x = ssp_f(acc[i][0]); o.y = ssp_f(acc[i][1]);
            o.z = ssp_f(acc[i][2]); o.w = ssp_f(acc[i][3]);
        } else {
            o.x = acc[i][0]; o.y = acc[i][1]; o.z = acc[i][2]; o.w = acc[i][3];
        }
        if (MODE == 2) {
            float4 p = *(const float4*)(out + n * 128 + c4);
            o.x += p.x; o.y += p.y; o.z += p.z; o.w += p.w;
        }
        *(float4*)(out + n * 128 + c4) = o;
    }
}

// ---------------- tiled fused edge kernel -------------------------------------
// USE_CSR=1: stream message to msgbuf[slot[e]]; USE_CSR=0: atomic scatter.
template<int USE_CSR>
__global__ __launch_bounds__(256) void edge_tiled(
    const float* __restrict__ posf,
    const int* __restrict__ row, const int* __restrict__ col,
    const float* __restrict__ eattrf,
    const float* __restrict__ w1, const float* __restrict__ b1,
    const float* __restrict__ w2, const float* __restrict__ b2,
    const float* __restrict__ xh, float* __restrict__ agg,
    const int* __restrict__ slot, float* __restrict__ msgbuf,
    int E, int NB, int F50, float delta, float coeff)
{
    __shared__ float ea_s[32][52];
    __shared__ float t_s[32][128];
    __shared__ int   row_s[32];
    __shared__ int   dst_s[32];
    __shared__ float C_s[32];
    __shared__ float ew_s[32];

    const int t = threadIdx.x;
    const long e0 = (long)blockIdx.x * 32;

    if (t < 32) {
        long e = e0 + t; if (e >= E) e = E - 1;
        const int r = row[e], c = col[e];
        row_s[t] = r;
        dst_s[t] = USE_CSR ? slot[e] : c;
        float dx = posf[r*3+0] - posf[c*3+0];
        float dy = posf[r*3+1] - posf[c*3+1];
        float dz = posf[r*3+2] - posf[c*3+2];
        float ew = sqrtf(dx*dx + dy*dy + dz*dz);
        ew_s[t] = ew;
        C_s[t]  = 0.5f * (cosf(ew * 0.3141592653589793f) + 1.0f);  // pi/10
        for (int q = 0; q < NB; ++q)
            ea_s[t][q] = eattrf[e * NB + q];
    }
    __syncthreads();
    {
        const int NGS = F50 - NB;
        for (int i = t; i < 32 * NGS; i += 256) {
            const int e = i / NGS, g = i - e * NGS;
            const float d = ew_s[e] - (float)g * delta;
            ea_s[e][NB + g] = __expf(coeff * d * d);
        }
    }
    __syncthreads();

    const int j   = t & 31;
    const int sub = t >> 5;
    const int c4  = j * 4;
    const int eb  = sub * 4;

    float acc[4][4];
    // ---- GEMM1: [32,F50] @ [F50,128] + b1 -> ssp -> t_s ----
    {
        const float4 bv = *(const float4*)(b1 + c4);
        #pragma unroll
        for (int i = 0; i < 4; ++i) { acc[i][0]=bv.x; acc[i][1]=bv.y; acc[i][2]=bv.z; acc[i][3]=bv.w; }
        for (int k = 0; k < F50; ++k) {
            const float4 wv = *(const float4*)(w1 + k * 128 + c4);
            #pragma unroll
            for (int i = 0; i < 4; ++i) {
                const float a = ea_s[eb + i][k];
                acc[i][0] += a * wv.x; acc[i][1] += a * wv.y;
                acc[i][2] += a * wv.z; acc[i][3] += a * wv.w;
            }
        }
        #pragma unroll
        for (int i = 0; i < 4; ++i) {
            float4 o;
            o.x = ssp_f(acc[i][0]); o.y = ssp_f(acc[i][1]);
            o.z = ssp_f(acc[i][2]); o.w = ssp_f(acc[i][3]);
            *(float4*)&t_s[eb + i][c4] = o;
        }
    }
    __syncthreads();

    // ---- GEMM2: [32,128] @ [128,128] + b2 ----
    {
        const float4 bv = *(const float4*)(b2 + c4);
        #pragma unroll
        for (int i = 0; i < 4; ++i) { acc[i][0]=bv.x; acc[i][1]=bv.y; acc[i][2]=bv.z; acc[i][3]=bv.w; }
        #pragma unroll 4
        for (int k = 0; k < 128; ++k) {
            const float4 wv = *(const float4*)(w2 + k * 128 + c4);
            #pragma unroll
            for (int i = 0; i < 4; ++i) {
                const float a = t_s[eb + i][k];
                acc[i][0] += a * wv.x; acc[i][1] += a * wv.y;
                acc[i][2] += a * wv.z; acc[i][3] += a * wv.w;
            }
        }
    }

    // ---- epilogue: W*C * xh[row] -> stream to msgbuf slot (or atomic) ----
    #pragma unroll
    for (int i = 0; i < 4; ++i) {
        const int e = eb + i;
        if (e0 + e >= E) continue;
        const float Ce = C_s[e];
        const float4 xv = *(const float4*)(xh + (long)row_s[e] * 128 + c4);
        if (USE_CSR) {
            float4 o;
            o.x = acc[i][0] * Ce * xv.x; o.y = acc[i][1] * Ce * xv.y;
            o.z = acc[i][2] * Ce * xv.z; o.w = acc[i][3] * Ce * xv.w;
            *(float4*)(msgbuf + (long)dst_s[e] * 128 + c4) = o;
        } else {
            float* ag = agg + (long)dst_s[e] * 128 + c4;
            atomicAdd(ag + 0, acc[i][0] * Ce * xv.x);
            atomicAdd(ag + 1, acc[i][1] * Ce * xv.y);
            atomicAdd(ag + 2, acc[i][2] * Ce * xv.z);
            atomicAdd(ag + 3, acc[i][3] * Ce * xv.w);
        }
    }
}

// ---------------- CSR gather: agg[n] = sum msgbuf[rowptr[n]..rowptr[n+1]) -----
__global__ __launch_bounds__(128) void gather_kernel(
    const float* __restrict__ msgbuf, const int* __restrict__ rowptr,
    float* __restrict__ agg)
{
    const int n = blockIdx.x;
    const int c = threadIdx.x;
    const int s0 = rowptr[n], s1 = rowptr[n + 1];
    float a = 0.f;
    for (int s = s0; s < s1; ++s)
        a += msgbuf[(long)s * 128 + c];
    agg[(long)n * 128 + c] = a;
}

// ---------------- readout ------------------------------------------------------
__global__ __launch_bounds__(128) void readout_simple(
    const float* __restrict__ h,
    const float* __restrict__ o1w, const float* __restrict__ o1b,
    const float* __restrict__ o2w, const float* __restrict__ o2b,
    const int* __restrict__ batch, float* __restrict__ accb)
{
    __shared__ float hr[128];
    __shared__ float vv[64];
    const int n = blockIdx.x;
    const int t = threadIdx.x;
    hr[t] = h[(long)n * 128 + t];
    __syncthreads();
    if (t < 64) {
        float a = o1b[t];
        #pragma unroll 8
        for (int k = 0; k < 128; ++k)
            a = fmaf(hr[k], o1w[k * 64 + t], a);
        vv[t] = ssp_f(a) * o2w[t];
    }
    __syncthreads();
    if (t < 32) vv[t] += vv[t + 32];
    __syncthreads();
    if (t < 16) vv[t] += vv[t + 16];
    __syncthreads();
    if (t < 8)  vv[t] += vv[t + 8];
    __syncthreads();
    if (t < 4)  vv[t] += vv[t + 4];
    __syncthreads();
    if (t < 2)  vv[t] += vv[t + 2];
    __syncthreads();
    if (t == 0) atomicAdd(&accb[batch[n]], vv[0] + vv[1] + o2b[0]);
}

// output is FLOAT32 (verified round 11)
__global__ void finalize_kernel(const float* __restrict__ accb,
                                float* __restrict__ out, int B)
{
    int t = blockIdx.x * 256 + threadIdx.x;
    if (t < B) out[t] = accb[t];
}

// ---------------- launch -------------------------------------------------------
extern "C" void kernel_launch(void* const* d_in, const int* in_sizes, int n_in,
                              void* d_out, int out_size, void* d_ws, size_t ws_size,
                              hipStream_t stream)
{
    const int N   = in_sizes[0];
    const int E   = in_sizes[3] / 2;
    const int B   = out_size;
    const int H   = 128;
    const int L   = in_sizes[7] / H;
    const int NB  = in_sizes[4] / E;
    const int F50 = in_sizes[6] / (L * H);
    const int NGS = F50 - NB;
    const float delta = 10.0f / (float)(NGS - 1);
    const float coeff = -0.5f / (delta * delta);

    const int fidx[16] = {1, 4, 5, 6, 7, 8, 9, 10, 11, 12, 13, 14, 15, 16, 17, 18};
    long foff[17]; foff[0] = 0;
    for (int i = 0; i < 16; ++i) foff[i + 1] = foff[i] + in_sizes[fidx[i]];

    float* F = (float*)d_ws;
    long base = (foff[16] + 3) & ~3L;
    float* h    = F + base;
    float* xh   = h + (long)N * H;
    float* agg  = xh + (long)N * H;
    float* accb = agg + (long)N * H;
    int*   flag  = (int*)(accb + ((B + 3) & ~3));
    int*   iflag = flag + 1;
    int*   zi     = flag + 4;
    int*   batchi = zi + N;
    int*   eidxi  = batchi + N;
    int*   count  = eidxi + 2 * E;
    int*   rowptr = count + N;          // N+1
    int*   next   = rowptr + N + 1;     // N
    int*   slot   = next + N;           // E
    long   used   = (long)(slot + E - (int*)d_ws);  // in 4-byte units
    long   msgoff = (used + 3) & ~3L;
    float* msgbuf = (float*)d_ws + msgoff;          // E*H floats
    const bool use_csr = ((msgoff + (long)E * H) * 4L <= (long)ws_size);

    sniff_kernel<<<1, 256, 0, stream>>>((const unsigned int*)d_in[5], flag);
    sniff_int_kernel<<<1, 128, 0, stream>>>((const unsigned int*)d_in[0], iflag);

    for (int i = 0; i < 16; ++i) {
        int n = in_sizes[fidx[i]];
        convert_kernel<<<(n + 255) / 256, 256, 0, stream>>>(d_in[fidx[i]], F + foff[i], n, flag);
    }
    convert_int_kernel<<<(N + 255) / 256, 256, 0, stream>>>(d_in[0], zi, N, iflag);
    convert_int_kernel<<<(N + 255) / 256, 256, 0, stream>>>(d_in[2], batchi, N, iflag);
    convert_int_kernel<<<(2 * E + 255) / 256, 256, 0, stream>>>(d_in[3], eidxi, 2 * E, iflag);

    const float* posf   = F + foff[0];
    const float* eattrf = F + foff[1];
    const float* embf   = F + foff[2];
    const float* w1   = F + foff[3];  const float* b1   = F + foff[4];
    const float* w2   = F + foff[5];  const float* b2   = F + foff[6];
    const float* cf1  = F + foff[7];  const float* cf2  = F + foff[8];
    const float* cf2b = F + foff[9];  const float* lin  = F + foff[10];
    const float* linb = F + foff[11]; const float* o1   = F + foff[12];
    const float* o1b  = F + foff[13]; const float* o2   = F + foff[14];
    const float* o2b  = F + foff[15];

    // CSR build (once per call)
    if (use_csr) {
        zero_int_kernel<<<(N + 255) / 256, 256, 0, stream>>>(count, N);
        hist_kernel<<<(E + 255) / 256, 256, 0, stream>>>(eidxi + E, count, E);
        scan_kernel<<<1, 256, 0, stream>>>(count, rowptr, next, N);
        slot_kernel<<<(E + 255) / 256, 256, 0, stream>>>(eidxi + E, next, slot, E);
    }

    embed_kernel<<<(N * H + 255) / 256, 256, 0, stream>>>(zi, embf, h, N * H);
    hipMemsetAsync(accb, 0, (size_t)B * sizeof(float), stream);

    const int ngemm = (N + 31) / 32;
    const int nedge = (E + 31) / 32;
    for (int l = 0; l < L; ++l) {
        node_gemm_tiled<0><<<ngemm, 256, 0, stream>>>(h, cf1 + (long)l * H * H, nullptr, xh, N);
        if (use_csr) {
            edge_tiled<1><<<nedge, 256, 0, stream>>>(
                posf, eidxi, eidxi + E, eattrf,
                w1 + (long)l * F50 * H, b1 + (long)l * H,
                w2 + (long)l * H * H,  b2 + (long)l * H,
                xh, agg, slot, msgbuf, E, NB, F50, delta, coeff);
            gather_kernel<<<N, 128, 0, stream>>>(msgbuf, rowptr, agg);
        } else {
            hipMemsetAsync(agg, 0, (size_t)N * H * sizeof(float), stream);
            edge_tiled<0><<<nedge, 256, 0, stream>>>(
                posf, eidxi, eidxi + E, eattrf,
                w1 + (long)l * F50 * H, b1 + (long)l * H,
                w2 + (long)l * H * H,  b2 + (long)l * H,
                xh, agg, slot, msgbuf, E, NB, F50, delta, coeff);
        }
        node_gemm_tiled<1><<<ngemm, 256, 0, stream>>>(agg, cf2 + (long)l * H * H, cf2b + (long)l * H, xh, N);
        node_gemm_tiled<2><<<ngemm, 256, 0, stream>>>(xh, lin + (long)l * H * H, linb + (long)l * H, h, N);
    }

    readout_simple<<<N, 128, 0, stream>>>(h, o1, o1b, o2, o2b, batchi, accb);
    finalize_kernel<<<(B + 255) / 256, 256, 0, stream>>>(accb, (float*)d_out, B);
}

// Round 14
// 2691.376 us; speedup vs baseline: 1.6156x; 1.6156x over previous
//
#include <hip/hip_runtime.h>
#include <hip/hip_bf16.h>

__device__ __forceinline__ float ssp_f(float x) {
    return fmaxf(x, 0.f) + log1pf(__expf(-fabsf(x))) - 0.6931471805599453f;
}

// ---------------- float dtype sniffer ----------------------------------------
__global__ void sniff_kernel(const unsigned int* __restrict__ raw, int* __restrict__ flag)
{
    __shared__ int cnt[256];
    const int t = threadIdx.x;
    unsigned int w = raw[t];
    unsigned int e = (w >> 7) & 0xFFu;
    cnt[t] = (e >= 100u && e <= 135u) ? 1 : 0;
    __syncthreads();
    for (int s = 128; s > 0; s >>= 1) {
        if (t < s) cnt[t] += cnt[t + s];
        __syncthreads();
    }
    if (t == 0) *flag = (cnt[0] >= 160) ? 1 : 0;   // 1 = floats are bf16
}

// ---------------- int width sniffer -------------------------------------------
__global__ void sniff_int_kernel(const unsigned int* __restrict__ z, int* __restrict__ iflag)
{
    __shared__ int cnt[128];
    const int t = threadIdx.x;
    cnt[t] = (z[2 * t + 1] == 0u) ? 1 : 0;
    __syncthreads();
    for (int s = 64; s > 0; s >>= 1) {
        if (t < s) cnt[t] += cnt[t + s];
        __syncthreads();
    }
    if (t == 0) *iflag = (cnt[0] >= 126) ? 1 : 0;  // 1 = ints are int64
}

// ---------------- converts -----------------------------------------------------
__global__ __launch_bounds__(256) void convert_kernel(
    const void* __restrict__ src, float* __restrict__ dst, int n,
    const int* __restrict__ flag)
{
    int i = blockIdx.x * 256 + threadIdx.x;
    if (i >= n) return;
    if (*flag) dst[i] = __bfloat162float(((const __hip_bfloat16*)src)[i]);
    else       dst[i] = ((const float*)src)[i];
}

__global__ __launch_bounds__(256) void convert_int_kernel(
    const void* __restrict__ src, int* __restrict__ dst, int n,
    const int* __restrict__ iflag)
{
    int i = blockIdx.x * 256 + threadIdx.x;
    if (i >= n) return;
    if (*iflag) dst[i] = (int)(((const long long*)src)[i]);
    else        dst[i] = ((const int*)src)[i];
}

// ---------------- node embedding gather ---------------------------------------
__global__ __launch_bounds__(256) void embed_kernel(
    const int* __restrict__ z, const float* __restrict__ embf,
    float* __restrict__ h, int NH)
{
    int idx = blockIdx.x * 256 + threadIdx.x;
    if (idx >= NH) return;
    h[idx] = embf[z[idx >> 7] * 128 + (idx & 127)];
}

// ---------------- CSR build ----------------------------------------------------
__global__ __launch_bounds__(256) void zero_int_kernel(int* p, int n)
{
    int i = blockIdx.x * 256 + threadIdx.x;
    if (i < n) p[i] = 0;
}

__global__ __launch_bounds__(256) void hist_kernel(const int* __restrict__ col,
                                                   int* __restrict__ count, int E)
{
    int e = blockIdx.x * 256 + threadIdx.x;
    if (e < E) atomicAdd(&count[col[e]], 1);
}

// single-block exclusive scan of count[N] -> rowptr[N+1], next[N]
__global__ __launch_bounds__(256) void scan_kernel(const int* __restrict__ count,
                                                   int* __restrict__ rowptr,
                                                   int* __restrict__ next, int N)
{
    __shared__ int part[256];
    const int t = threadIdx.x;
    const int chunk = (N + 255) / 256;
    const int lo = t * chunk, hi = min(lo + chunk, N);
    int s = 0;
    for (int i = lo; i < hi; ++i) s += count[i];
    part[t] = s;
    __syncthreads();
    if (t == 0) {
        int run = 0;
        for (int i = 0; i < 256; ++i) { int v = part[i]; part[i] = run; run += v; }
        rowptr[N] = run;
    }
    __syncthreads();
    int run = part[t];
    for (int i = lo; i < hi; ++i) {
        rowptr[i] = run; next[i] = run;
        run += count[i];
    }
}

__global__ __launch_bounds__(256) void slot_kernel(const int* __restrict__ col,
                                                   int* __restrict__ next,
                                                   int* __restrict__ slot, int E)
{
    int e = blockIdx.x * 256 + threadIdx.x;
    if (e < E) slot[e] = atomicAdd(&next[col[e]], 1);
}

__global__ __launch_bounds__(256) void perm_kernel(const int* __restrict__ slot,
                                                   int* __restrict__ perm, int E)
{
    int e = blockIdx.x * 256 + threadIdx.x;
    if (e < E) perm[slot[e]] = e;
}

// ---------------- tiled node GEMM [N,128]@[128,128] ---------------------------
template<int MODE>
__global__ __launch_bounds__(256) void node_gemm_tiled(
    const float* __restrict__ in, const float* __restrict__ W,
    const float* __restrict__ bias, float* __restrict__ out, int N)
{
    __shared__ float in_s[32][128];
    const int t = threadIdx.x;
    const long n0 = (long)blockIdx.x * 32;
    for (int i = t; i < 32 * 128; i += 256) {
        long n = n0 + (i >> 7);
        in_s[i >> 7][i & 127] = (n < N) ? in[n * 128 + (i & 127)] : 0.f;
    }
    __syncthreads();
    const int j = t & 31, sub = t >> 5;
    const int c4 = j * 4, rb = sub * 4;
    float acc[4][4];
    float4 bv = make_float4(0.f, 0.f, 0.f, 0.f);
    if (MODE != 0) bv = *(const float4*)(bias + c4);
    #pragma unroll
    for (int i = 0; i < 4; ++i) { acc[i][0]=bv.x; acc[i][1]=bv.y; acc[i][2]=bv.z; acc[i][3]=bv.w; }
    #pragma unroll 4
    for (int k = 0; k < 128; ++k) {
        const float4 wv = *(const float4*)(W + k * 128 + c4);
        #pragma unroll
        for (int i = 0; i < 4; ++i) {
            const float a = in_s[rb + i][k];
            acc[i][0] += a * wv.x; acc[i][1] += a * wv.y;
            acc[i][2] += a * wv.z; acc[i][3] += a * wv.w;
        }
    }
    #pragma unroll
    for (int i = 0; i < 4; ++i) {
        long n = n0 + rb + i;
        if (n >= N) continue;
        float4 o;
        if (MODE == 1) {
            o.x = ssp_f(acc[i][0]); o.y = ssp_f(acc[i][1]);
            o.z = ssp_f(acc[i][2]); o.w = ssp_f(acc[i][3]);
        } else {
            o.x = acc[i][0]; o.y = acc[i][1]; o.z = acc[i][2]; o.w = acc[i][3];
        }
        if (MODE == 2) {
            float4 p = *(const float4*)(out + n * 128 + c4);
            o.x += p.x; o.y += p.y; o.z += p.z; o.w += p.w;
        }
        *(float4*)(out + n * 128 + c4) = o;
    }
}

// ---------------- tiled fused edge kernel -------------------------------------
// SORTED=1: edges visited in col-sorted order (via perm); per-thread register
//   run-collapse -> LDS run accumulator -> 1 global atomic per run per block.
// SORTED=0: direct atomic scatter (fallback).
template<int SORTED>
__global__ __launch_bounds__(256) void edge_tiled(
    const float* __restrict__ posf,
    const int* __restrict__ row, const int* __restrict__ col,
    const float* __restrict__ eattrf,
    const int* __restrict__ perm,
    const float* __restrict__ w1, const float* __restrict__ b1,
    const float* __restrict__ w2, const float* __restrict__ b2,
    const float* __restrict__ xh, float* __restrict__ agg,
    int E, int NB, int F50, float delta, float coeff)
{
    __shared__ float ea_s[32][52];
    __shared__ float t_s[32][128];
    __shared__ int   row_s[32];
    __shared__ int   col_s[32];
    __shared__ float C_s[32];
    __shared__ float ew_s[32];
    __shared__ int   rid_s[32];
    __shared__ int   runcol_s[32];
    __shared__ int   nruns_s;
    __shared__ float runbuf[32][128];   // only used when SORTED

    const int t = threadIdx.x;
    const long p0 = (long)blockIdx.x * 32;

    if (t < 32) {
        long p = p0 + t;
        const bool valid = (p < E);
        const long e = SORTED ? (long)perm[valid ? p : (E - 1)] : (valid ? p : (E - 1));
        const int r = row[e], c = col[e];
        row_s[t] = r; col_s[t] = c;
        float dx = posf[r*3+0] - posf[c*3+0];
        float dy = posf[r*3+1] - posf[c*3+1];
        float dz = posf[r*3+2] - posf[c*3+2];
        float ew = sqrtf(dx*dx + dy*dy + dz*dz);
        ew_s[t] = ew;
        C_s[t]  = valid ? 0.5f * (cosf(ew * 0.3141592653589793f) + 1.0f) : 0.f;
        for (int q = 0; q < NB; ++q)
            ea_s[t][q] = eattrf[e * NB + q];
    }
    __syncthreads();
    if (SORTED) {
        if (t == 0) {
            int nr = 0;
            for (int i = 0; i < 32; ++i) {
                if (i == 0 || col_s[i] != col_s[i - 1]) { runcol_s[nr] = col_s[i]; ++nr; }
                rid_s[i] = nr - 1;
            }
            nruns_s = nr;
        }
        for (int i = t; i < 32 * 128; i += 256)
            ((float*)runbuf)[i] = 0.f;
    }
    {
        const int NGS = F50 - NB;
        for (int i = t; i < 32 * NGS; i += 256) {
            const int e = i / NGS, g = i - e * NGS;
            const float d = ew_s[e] - (float)g * delta;
            ea_s[e][NB + g] = __expf(coeff * d * d);
        }
    }
    __syncthreads();

    const int j   = t & 31;
    const int sub = t >> 5;
    const int c4  = j * 4;
    const int eb  = sub * 4;

    float acc[4][4];
    // ---- GEMM1: [32,F50] @ [F50,128] + b1 -> ssp -> t_s ----
    {
        const float4 bv = *(const float4*)(b1 + c4);
        #pragma unroll
        for (int i = 0; i < 4; ++i) { acc[i][0]=bv.x; acc[i][1]=bv.y; acc[i][2]=bv.z; acc[i][3]=bv.w; }
        for (int k = 0; k < F50; ++k) {
            const float4 wv = *(const float4*)(w1 + k * 128 + c4);
            #pragma unroll
            for (int i = 0; i < 4; ++i) {
                const float a = ea_s[eb + i][k];
                acc[i][0] += a * wv.x; acc[i][1] += a * wv.y;
                acc[i][2] += a * wv.z; acc[i][3] += a * wv.w;
            }
        }
        #pragma unroll
        for (int i = 0; i < 4; ++i) {
            float4 o;
            o.x = ssp_f(acc[i][0]); o.y = ssp_f(acc[i][1]);
            o.z = ssp_f(acc[i][2]); o.w = ssp_f(acc[i][3]);
            *(float4*)&t_s[eb + i][c4] = o;
        }
    }
    __syncthreads();

    // ---- GEMM2: [32,128] @ [128,128] + b2 ----
    {
        const float4 bv = *(const float4*)(b2 + c4);
        #pragma unroll
        for (int i = 0; i < 4; ++i) { acc[i][0]=bv.x; acc[i][1]=bv.y; acc[i][2]=bv.z; acc[i][3]=bv.w; }
        #pragma unroll 4
        for (int k = 0; k < 128; ++k) {
            const float4 wv = *(const float4*)(w2 + k * 128 + c4);
            #pragma unroll
            for (int i = 0; i < 4; ++i) {
                const float a = t_s[eb + i][k];
                acc[i][0] += a * wv.x; acc[i][1] += a * wv.y;
                acc[i][2] += a * wv.z; acc[i][3] += a * wv.w;
            }
        }
    }

    // ---- epilogue ----
    if (SORTED) {
        float carry0 = 0.f, carry1 = 0.f, carry2 = 0.f, carry3 = 0.f;
        #pragma unroll
        for (int i = 0; i < 4; ++i) {
            const int e = eb + i;
            const float Ce = C_s[e];
            const float4 xv = *(const float4*)(xh + (long)row_s[e] * 128 + c4);
            carry0 += acc[i][0] * Ce * xv.x;
            carry1 += acc[i][1] * Ce * xv.y;
            carry2 += acc[i][2] * Ce * xv.z;
            carry3 += acc[i][3] * Ce * xv.w;
            const bool flush = (i == 3) || (col_s[e + 1] != col_s[e]);
            if (flush) {
                float* rb = &runbuf[rid_s[e]][c4];
                atomicAdd(rb + 0, carry0);
                atomicAdd(rb + 1, carry1);
                atomicAdd(rb + 2, carry2);
                atomicAdd(rb + 3, carry3);
                carry0 = carry1 = carry2 = carry3 = 0.f;
            }
        }
        __syncthreads();
        const int nr = nruns_s;
        const int cc = t & 127;
        for (int r = t >> 7; r < nr; r += 2)
            atomicAdd(&agg[(long)runcol_s[r] * 128 + cc], runbuf[r][cc]);
    } else {
        #pragma unroll
        for (int i = 0; i < 4; ++i) {
            const int e = eb + i;
            if (p0 + e >= E) continue;
            const float Ce = C_s[e];
            const float4 xv = *(const float4*)(xh + (long)row_s[e] * 128 + c4);
            float* ag = agg + (long)col_s[e] * 128 + c4;
            atomicAdd(ag + 0, acc[i][0] * Ce * xv.x);
            atomicAdd(ag + 1, acc[i][1] * Ce * xv.y);
            atomicAdd(ag + 2, acc[i][2] * Ce * xv.z);
            atomicAdd(ag + 3, acc[i][3] * Ce * xv.w);
        }
    }
}

// ---------------- readout ------------------------------------------------------
__global__ __launch_bounds__(128) void readout_simple(
    const float* __restrict__ h,
    const float* __restrict__ o1w, const float* __restrict__ o1b,
    const float* __restrict__ o2w, const float* __restrict__ o2b,
    const int* __restrict__ batch, float* __restrict__ accb)
{
    __shared__ float hr[128];
    __shared__ float vv[64];
    const int n = blockIdx.x;
    const int t = threadIdx.x;
    hr[t] = h[(long)n * 128 + t];
    __syncthreads();
    if (t < 64) {
        float a = o1b[t];
        #pragma unroll 8
        for (int k = 0; k < 128; ++k)
            a = fmaf(hr[k], o1w[k * 64 + t], a);
        vv[t] = ssp_f(a) * o2w[t];
    }
    __syncthreads();
    if (t < 32) vv[t] += vv[t + 32];
    __syncthreads();
    if (t < 16) vv[t] += vv[t + 16];
    __syncthreads();
    if (t < 8)  vv[t] += vv[t + 8];
    __syncthreads();
    if (t < 4)  vv[t] += vv[t + 4];
    __syncthreads();
    if (t < 2)  vv[t] += vv[t + 2];
    __syncthreads();
    if (t == 0) atomicAdd(&accb[batch[n]], vv[0] + vv[1] + o2b[0]);
}

// output is FLOAT32 (verified round 11)
__global__ void finalize_kernel(const float* __restrict__ accb,
                                float* __restrict__ out, int B)
{
    int t = blockIdx.x * 256 + threadIdx.x;
    if (t < B) out[t] = accb[t];
}

// ---------------- launch -------------------------------------------------------
extern "C" void kernel_launch(void* const* d_in, const int* in_sizes, int n_in,
                              void* d_out, int out_size, void* d_ws, size_t ws_size,
                              hipStream_t stream)
{
    const int N   = in_sizes[0];
    const int E   = in_sizes[3] / 2;
    const int B   = out_size;
    const int H   = 128;
    const int L   = in_sizes[7] / H;
    const int NB  = in_sizes[4] / E;
    const int F50 = in_sizes[6] / (L * H);
    const int NGS = F50 - NB;
    const float delta = 10.0f / (float)(NGS - 1);
    const float coeff = -0.5f / (delta * delta);

    const int fidx[16] = {1, 4, 5, 6, 7, 8, 9, 10, 11, 12, 13, 14, 15, 16, 17, 18};
    long foff[17]; foff[0] = 0;
    for (int i = 0; i < 16; ++i) foff[i + 1] = foff[i] + in_sizes[fidx[i]];

    float* F = (float*)d_ws;
    long base = (foff[16] + 3) & ~3L;
    float* h    = F + base;
    float* xh   = h + (long)N * H;
    float* agg  = xh + (long)N * H;
    float* accb = agg + (long)N * H;
    int*   flag  = (int*)(accb + ((B + 3) & ~3));
    int*   iflag = flag + 1;
    int*   zi     = flag + 4;
    int*   batchi = zi + N;
    int*   eidxi  = batchi + N;
    int*   count  = eidxi + 2 * E;
    int*   rowptr = count + N;          // N+1
    int*   next   = rowptr + N + 1;     // N
    int*   slot   = next + N;           // E
    int*   perm   = slot + E;           // E
    long   used4  = (long)(perm + E - (int*)d_ws);  // 4-byte units
    const bool use_sorted = (used4 * 4L <= (long)ws_size);

    sniff_kernel<<<1, 256, 0, stream>>>((const unsigned int*)d_in[5], flag);
    sniff_int_kernel<<<1, 128, 0, stream>>>((const unsigned int*)d_in[0], iflag);

    for (int i = 0; i < 16; ++i) {
        int n = in_sizes[fidx[i]];
        convert_kernel<<<(n + 255) / 256, 256, 0, stream>>>(d_in[fidx[i]], F + foff[i], n, flag);
    }
    convert_int_kernel<<<(N + 255) / 256, 256, 0, stream>>>(d_in[0], zi, N, iflag);
    convert_int_kernel<<<(N + 255) / 256, 256, 0, stream>>>(d_in[2], batchi, N, iflag);
    convert_int_kernel<<<(2 * E + 255) / 256, 256, 0, stream>>>(d_in[3], eidxi, 2 * E, iflag);

    const float* posf   = F + foff[0];
    const float* eattrf = F + foff[1];
    const float* embf   = F + foff[2];
    const float* w1   = F + foff[3];  const float* b1   = F + foff[4];
    const float* w2   = F + foff[5];  const float* b2   = F + foff[6];
    const float* cf1  = F + foff[7];  const float* cf2  = F + foff[8];
    const float* cf2b = F + foff[9];  const float* lin  = F + foff[10];
    const float* linb = F + foff[11]; const float* o1   = F + foff[12];
    const float* o1b  = F + foff[13]; const float* o2   = F + foff[14];
    const float* o2b  = F + foff[15];

    if (use_sorted) {
        zero_int_kernel<<<(N + 255) / 256, 256, 0, stream>>>(count, N);
        hist_kernel<<<(E + 255) / 256, 256, 0, stream>>>(eidxi + E, count, E);
        scan_kernel<<<1, 256, 0, stream>>>(count, rowptr, next, N);
        slot_kernel<<<(E + 255) / 256, 256, 0, stream>>>(eidxi + E, next, slot, E);
        perm_kernel<<<(E + 255) / 256, 256, 0, stream>>>(slot, perm, E);
    }

    embed_kernel<<<(N * H + 255) / 256, 256, 0, stream>>>(zi, embf, h, N * H);
    hipMemsetAsync(accb, 0, (size_t)B * sizeof(float), stream);

    const int ngemm = (N + 31) / 32;
    const int nedge = (E + 31) / 32;
    for (int l = 0; l < L; ++l) {
        hipMemsetAsync(agg, 0, (size_t)N * H * sizeof(float), stream);
        node_gemm_tiled<0><<<ngemm, 256, 0, stream>>>(h, cf1 + (long)l * H * H, nullptr, xh, N);
        if (use_sorted) {
            edge_tiled<1><<<nedge, 256, 0, stream>>>(
                posf, eidxi, eidxi + E, eattrf, perm,
                w1 + (long)l * F50 * H, b1 + (long)l * H,
                w2 + (long)l * H * H,  b2 + (long)l * H,
                xh, agg, E, NB, F50, delta, coeff);
        } else {
            edge_tiled<0><<<nedge, 256, 0, stream>>>(
                posf, eidxi, eidxi + E, eattrf, perm,
                w1 + (long)l * F50 * H, b1 + (long)l * H,
                w2 + (long)l * H * H,  b2 + (long)l * H,
                xh, agg, E, NB, F50, delta, coeff);
        }
        node_gemm_tiled<1><<<ngemm, 256, 0, stream>>>(agg, cf2 + (long)l * H * H, cf2b + (long)l * H, xh, N);
        node_gemm_tiled<2><<<ngemm, 256, 0, stream>>>(xh, lin + (long)l * H * H, linb + (long)l * H, h, N);
    }

    readout_simple<<<N, 128, 0, stream>>>(h, o1, o1b, o2, o2b, batchi, accb);
    finalize_kernel<<<(B + 255) / 256, 256, 0, stream>>>(accb, (float*)d_out, B);
}

// Round 15
// 1859.676 us; speedup vs baseline: 2.3382x; 1.4472x over previous
//
#include <hip/hip_runtime.h>
#include <hip/hip_bf16.h>

typedef __attribute__((ext_vector_type(8))) short bfrag;
typedef __attribute__((ext_vector_type(4))) float f32x4;

__device__ __forceinline__ float ssp_f(float x) {
    return fmaxf(x, 0.f) + log1pf(__expf(-fabsf(x))) - 0.6931471805599453f;
}

__device__ __forceinline__ unsigned short f2b(float x) {
    __hip_bfloat16 h = __float2bfloat16(x);
    return *(unsigned short*)&h;
}

// ---------------- float dtype sniffer ----------------------------------------
__global__ void sniff_kernel(const unsigned int* __restrict__ raw, int* __restrict__ flag)
{
    __shared__ int cnt[256];
    const int t = threadIdx.x;
    unsigned int w = raw[t];
    unsigned int e = (w >> 7) & 0xFFu;
    cnt[t] = (e >= 100u && e <= 135u) ? 1 : 0;
    __syncthreads();
    for (int s = 128; s > 0; s >>= 1) {
        if (t < s) cnt[t] += cnt[t + s];
        __syncthreads();
    }
    if (t == 0) *flag = (cnt[0] >= 160) ? 1 : 0;   // 1 = floats are bf16
}

// ---------------- int width sniffer -------------------------------------------
__global__ void sniff_int_kernel(const unsigned int* __restrict__ z, int* __restrict__ iflag)
{
    __shared__ int cnt[128];
    const int t = threadIdx.x;
    cnt[t] = (z[2 * t + 1] == 0u) ? 1 : 0;
    __syncthreads();
    for (int s = 64; s > 0; s >>= 1) {
        if (t < s) cnt[t] += cnt[t + s];
        __syncthreads();
    }
    if (t == 0) *iflag = (cnt[0] >= 126) ? 1 : 0;  // 1 = ints are int64
}

// ---------------- converts -----------------------------------------------------
__global__ __launch_bounds__(256) void convert_kernel(
    const void* __restrict__ src, float* __restrict__ dst, int n,
    const int* __restrict__ flag)
{
    int i = blockIdx.x * 256 + threadIdx.x;
    if (i >= n) return;
    if (*flag) dst[i] = __bfloat162float(((const __hip_bfloat16*)src)[i]);
    else       dst[i] = ((const float*)src)[i];
}

__global__ __launch_bounds__(256) void convert_int_kernel(
    const void* __restrict__ src, int* __restrict__ dst, int n,
    const int* __restrict__ iflag)
{
    int i = blockIdx.x * 256 + threadIdx.x;
    if (i >= n) return;
    if (*iflag) dst[i] = (int)(((const long long*)src)[i]);
    else        dst[i] = ((const int*)src)[i];
}

// ---------------- node embedding gather ---------------------------------------
__global__ __launch_bounds__(256) void embed_kernel(
    const int* __restrict__ z, const float* __restrict__ embf,
    float* __restrict__ h, int NH)
{
    int idx = blockIdx.x * 256 + threadIdx.x;
    if (idx >= NH) return;
    h[idx] = embf[z[idx >> 7] * 128 + (idx & 127)];
}

// ---------------- CSR build ----------------------------------------------------
__global__ __launch_bounds__(256) void zero_int_kernel(int* p, int n)
{
    int i = blockIdx.x * 256 + threadIdx.x;
    if (i < n) p[i] = 0;
}

__global__ __launch_bounds__(256) void hist_kernel(const int* __restrict__ col,
                                                   int* __restrict__ count, int E)
{
    int e = blockIdx.x * 256 + threadIdx.x;
    if (e < E) atomicAdd(&count[col[e]], 1);
}

__global__ __launch_bounds__(256) void scan_kernel(const int* __restrict__ count,
                                                   int* __restrict__ rowptr,
                                                   int* __restrict__ next, int N)
{
    __shared__ int part[256];
    const int t = threadIdx.x;
    const int chunk = (N + 255) / 256;
    const int lo = t * chunk, hi = min(lo + chunk, N);
    int s = 0;
    for (int i = lo; i < hi; ++i) s += count[i];
    part[t] = s;
    __syncthreads();
    if (t == 0) {
        int run = 0;
        for (int i = 0; i < 256; ++i) { int v = part[i]; part[i] = run; run += v; }
        rowptr[N] = run;
    }
    __syncthreads();
    int run = part[t];
    for (int i = lo; i < hi; ++i) {
        rowptr[i] = run; next[i] = run;
        run += count[i];
    }
}

__global__ __launch_bounds__(256) void slot_kernel(const int* __restrict__ col,
                                                   int* __restrict__ next,
                                                   int* __restrict__ slot, int E)
{
    int e = blockIdx.x * 256 + threadIdx.x;
    if (e < E) slot[e] = atomicAdd(&next[col[e]], 1);
}

__global__ __launch_bounds__(256) void perm_kernel(const int* __restrict__ slot,
                                                   int* __restrict__ perm, int E)
{
    int e = blockIdx.x * 256 + threadIdx.x;
    if (e < E) perm[slot[e]] = e;
}

// ---------------- pre-permute edge data into sorted order ---------------------
__global__ __launch_bounds__(256) void prep_edges_kernel(
    const float* __restrict__ posf, const int* __restrict__ row,
    const int* __restrict__ col, const float* __restrict__ eattrf,
    const int* __restrict__ perm,
    int* __restrict__ rowS, int* __restrict__ colS,
    float* __restrict__ CS, float* __restrict__ ewS,
    unsigned short* __restrict__ eaS, int E, int NB)
{
    int p = blockIdx.x * 256 + threadIdx.x;
    if (p >= E) return;
    const int e = perm[p];
    const int r = row[e], c = col[e];
    float dx = posf[r*3+0] - posf[c*3+0];
    float dy = posf[r*3+1] - posf[c*3+1];
    float dz = posf[r*3+2] - posf[c*3+2];
    float ew = sqrtf(dx*dx + dy*dy + dz*dz);
    rowS[p] = r; colS[p] = c; ewS[p] = ew;
    CS[p] = 0.5f * (cosf(ew * 0.3141592653589793f) + 1.0f);
    unsigned short* o = eaS + (long)p * 4;
    for (int q = 0; q < 4; ++q)
        o[q] = (q < NB) ? f2b(eattrf[(long)e * NB + q]) : (unsigned short)0;
}

// ---------------- weight transpose to bf16 N-major ----------------------------
// dst[n*Kpad + k] = bf16(src[k*N + n]), zero for k >= K
__global__ __launch_bounds__(256) void wtrans_kernel(
    const float* __restrict__ src, unsigned short* __restrict__ dst,
    int K, int Kpad, int N)
{
    int idx = blockIdx.x * 256 + threadIdx.x;
    if (idx >= N * Kpad) return;
    int n = idx / Kpad, k = idx - n * Kpad;
    dst[idx] = (k < K) ? f2b(src[k * N + n]) : (unsigned short)0;
}

// ---------------- tiled node GEMM [N,128]@[128,128] (fp32) --------------------
template<int MODE>
__global__ __launch_bounds__(256) void node_gemm_tiled(
    const float* __restrict__ in, const float* __restrict__ W,
    const float* __restrict__ bias, float* __restrict__ out, int N)
{
    __shared__ float in_s[32][128];
    const int t = threadIdx.x;
    const long n0 = (long)blockIdx.x * 32;
    for (int i = t; i < 32 * 128; i += 256) {
        long n = n0 + (i >> 7);
        in_s[i >> 7][i & 127] = (n < N) ? in[n * 128 + (i & 127)] : 0.f;
    }
    __syncthreads();
    const int j = t & 31, sub = t >> 5;
    const int c4 = j * 4, rb = sub * 4;
    float acc[4][4];
    float4 bv = make_float4(0.f, 0.f, 0.f, 0.f);
    if (MODE != 0) bv = *(const float4*)(bias + c4);
    #pragma unroll
    for (int i = 0; i < 4; ++i) { acc[i][0]=bv.x; acc[i][1]=bv.y; acc[i][2]=bv.z; acc[i][3]=bv.w; }
    #pragma unroll 4
    for (int k = 0; k < 128; ++k) {
        const float4 wv = *(const float4*)(W + k * 128 + c4);
        #pragma unroll
        for (int i = 0; i < 4; ++i) {
            const float a = in_s[rb + i][k];
            acc[i][0] += a * wv.x; acc[i][1] += a * wv.y;
            acc[i][2] += a * wv.z; acc[i][3] += a * wv.w;
        }
    }
    #pragma unroll
    for (int i = 0; i < 4; ++i) {
        long n = n0 + rb + i;
        if (n >= N) continue;
        float4 o;
        if (MODE == 1) {
            o.x = ssp_f(acc[i][0]); o.y = ssp_f(acc[i][1]);
            o.z = ssp_f(acc[i][2]); o.w = ssp_f(acc[i][3]);
        } else {
            o.x = acc[i][0]; o.y = acc[i][1]; o.z = acc[i][2]; o.w = acc[i][3];
        }
        if (MODE == 2) {
            float4 p = *(const float4*)(out + n * 128 + c4);
            o.x += p.x; o.y += p.y; o.z += p.z; o.w += p.w;
        }
        *(float4*)(out + n * 128 + c4) = o;
    }
}

// ---------------- MFMA edge kernel (sorted order) -----------------------------
// 32 edges/block, 256 threads = 4 waves. bf16 MFMA 16x16x32 for both GEMMs.
// Wave w: m0=(w&1)*16; tiles tt=0..3 at n0=((w>>1)*4+tt)*16.
// Verified layouts (m89/m120): A[m=lane&15][k=quad*8+j]; B[n=lane&15][k=quad*8+j]
// (weights pre-transposed N-major); D: row=quad*4+reg, col=lane&15.
__global__ __launch_bounds__(256) void edge_mfma(
    const int* __restrict__ rowS, const int* __restrict__ colS,
    const float* __restrict__ CS, const float* __restrict__ ewS,
    const unsigned short* __restrict__ eaS,
    const unsigned short* __restrict__ w1t, const float* __restrict__ b1,
    const unsigned short* __restrict__ w2t, const float* __restrict__ b2,
    const float* __restrict__ xh, float* __restrict__ agg,
    int E, int NB, int F50, float delta, float coeff)
{
    __shared__ __align__(16) short ea_b[32][64];   // bf16, K-padded to 64
    __shared__ __align__(16) short t_b[32][128];   // bf16 GEMM1 output
    __shared__ float runbuf[32][128];
    __shared__ int   row_s[32];
    __shared__ int   col_s[32];
    __shared__ float C_s[32];
    __shared__ float ew_s[32];
    __shared__ int   rid_s[32];
    __shared__ int   runcol_s[32];
    __shared__ int   nruns_s;

    const int t = threadIdx.x;
    const long p0 = (long)blockIdx.x * 32;

    if (t < 32) {
        long p = p0 + t; if (p >= E) p = E - 1;
        row_s[t] = rowS[p];
        col_s[t] = colS[p];
        C_s[t]   = (p0 + t < E) ? CS[p] : 0.f;
        ew_s[t]  = ewS[p];
    }
    __syncthreads();
    if (t == 0) {
        int nr = 0;
        for (int i = 0; i < 32; ++i) {
            if (i == 0 || col_s[i] != col_s[i - 1]) { runcol_s[nr] = col_s[i]; ++nr; }
            rid_s[i] = nr - 1;
        }
        nruns_s = nr;
    }
    for (int i = t; i < 32 * 128; i += 256)
        ((float*)runbuf)[i] = 0.f;
    // fill ea_b (bf16): [0,NB) from eaS, [NB,F50) gaussians, rest zero
    for (int i = t; i < 32 * 64; i += 256) {
        const int e = i >> 6, k = i & 63;
        long p = p0 + e; if (p >= E) p = E - 1;
        unsigned short v;
        if (k < NB)        v = eaS[p * 4 + k];
        else if (k < F50) {
            float d = ew_s[e] - (float)(k - NB) * delta;
            v = f2b(__expf(coeff * d * d));
        } else             v = 0;
        ea_b[e][k] = (short)v;
    }
    __syncthreads();

    const int lane = t & 63;
    const int w    = t >> 6;
    const int colL = lane & 15;
    const int quad = lane >> 4;
    const int m0   = (w & 1) * 16;

    // ---- GEMM1: ea[32x64pad] @ w1t -> ssp -> t_b (bf16) ----
    {
        f32x4 acc[4];
        #pragma unroll
        for (int tt = 0; tt < 4; ++tt) acc[tt] = (f32x4){0.f, 0.f, 0.f, 0.f};
        #pragma unroll
        for (int ks = 0; ks < 2; ++ks) {
            const bfrag a = *(const bfrag*)&ea_b[m0 + colL][ks * 32 + quad * 8];
            #pragma unroll
            for (int tt = 0; tt < 4; ++tt) {
                const int n0 = ((w >> 1) * 4 + tt) * 16;
                const bfrag b = *(const bfrag*)&w1t[(long)(n0 + colL) * 64 + ks * 32 + quad * 8];
                acc[tt] = __builtin_amdgcn_mfma_f32_16x16x32_bf16(a, b, acc[tt], 0, 0, 0);
            }
        }
        #pragma unroll
        for (int tt = 0; tt < 4; ++tt) {
            const int n0 = ((w >> 1) * 4 + tt) * 16;
            const float bcol = b1[n0 + colL];
            #pragma unroll
            for (int reg = 0; reg < 4; ++reg) {
                float v = ssp_f(acc[tt][reg] + bcol);
                t_b[m0 + quad * 4 + reg][n0 + colL] = (short)f2b(v);
            }
        }
    }
    __syncthreads();

    // ---- GEMM2: t_b[32x128] @ w2t + epilogue ----
    {
        f32x4 acc[4];
        #pragma unroll
        for (int tt = 0; tt < 4; ++tt) acc[tt] = (f32x4){0.f, 0.f, 0.f, 0.f};
        #pragma unroll
        for (int ks = 0; ks < 4; ++ks) {
            const bfrag a = *(const bfrag*)&t_b[m0 + colL][ks * 32 + quad * 8];
            #pragma unroll
            for (int tt = 0; tt < 4; ++tt) {
                const int n0 = ((w >> 1) * 4 + tt) * 16;
                const bfrag b = *(const bfrag*)&w2t[(long)(n0 + colL) * 128 + ks * 32 + quad * 8];
                acc[tt] = __builtin_amdgcn_mfma_f32_16x16x32_bf16(a, b, acc[tt], 0, 0, 0);
            }
        }
        const int ebase = m0 + quad * 4;
        #pragma unroll
        for (int tt = 0; tt < 4; ++tt) {
            const int n0 = ((w >> 1) * 4 + tt) * 16;
            const int cg = n0 + colL;
            const float bcol = b2[cg];
            float carry = 0.f;
            #pragma unroll
            for (int reg = 0; reg < 4; ++reg) {
                const int e = ebase + reg;
                const float v = acc[tt][reg] + bcol;
                carry += v * C_s[e] * xh[(long)row_s[e] * 128 + cg];
                if (reg == 3 || col_s[e + 1] != col_s[e]) {
                    atomicAdd(&runbuf[rid_s[e]][cg], carry);
                    carry = 0.f;
                }
            }
        }
    }
    __syncthreads();

    const int nr = nruns_s;
    const int cc = t & 127;
    for (int r = t >> 7; r < nr; r += 2)
        atomicAdd(&agg[(long)runcol_s[r] * 128 + cc], runbuf[r][cc]);
}

// ---------------- fp32 atomic edge kernel (fallback) --------------------------
__global__ __launch_bounds__(256) void edge_atomic(
    const float* __restrict__ posf,
    const int* __restrict__ row, const int* __restrict__ col,
    const float* __restrict__ eattrf,
    const float* __restrict__ w1, const float* __restrict__ b1,
    const float* __restrict__ w2, const float* __restrict__ b2,
    const float* __restrict__ xh, float* __restrict__ agg,
    int E, int NB, int F50, float delta, float coeff)
{
    __shared__ float ea_s[32][52];
    __shared__ float t_s[32][128];
    __shared__ int   row_s[32];
    __shared__ int   col_s[32];
    __shared__ float C_s[32];
    __shared__ float ew_s[32];

    const int t = threadIdx.x;
    const long e0 = (long)blockIdx.x * 32;

    if (t < 32) {
        long e = e0 + t; if (e >= E) e = E - 1;
        const int r = row[e], c = col[e];
        row_s[t] = r; col_s[t] = c;
        float dx = posf[r*3+0] - posf[c*3+0];
        float dy = posf[r*3+1] - posf[c*3+1];
        float dz = posf[r*3+2] - posf[c*3+2];
        float ew = sqrtf(dx*dx + dy*dy + dz*dz);
        ew_s[t] = ew;
        C_s[t]  = (e0 + t < E) ? 0.5f * (cosf(ew * 0.3141592653589793f) + 1.0f) : 0.f;
        for (int q = 0; q < NB; ++q)
            ea_s[t][q] = eattrf[e * NB + q];
    }
    __syncthreads();
    {
        const int NGS = F50 - NB;
        for (int i = t; i < 32 * NGS; i += 256) {
            const int e = i / NGS, g = i - e * NGS;
            const float d = ew_s[e] - (float)g * delta;
            ea_s[e][NB + g] = __expf(coeff * d * d);
        }
    }
    __syncthreads();

    const int j = t & 31, sub = t >> 5;
    const int c4 = j * 4, eb = sub * 4;
    float acc[4][4];
    {
        const float4 bv = *(const float4*)(b1 + c4);
        #pragma unroll
        for (int i = 0; i < 4; ++i) { acc[i][0]=bv.x; acc[i][1]=bv.y; acc[i][2]=bv.z; acc[i][3]=bv.w; }
        for (int k = 0; k < F50; ++k) {
            const float4 wv = *(const float4*)(w1 + k * 128 + c4);
            #pragma unroll
            for (int i = 0; i < 4; ++i) {
                const float a = ea_s[eb + i][k];
                acc[i][0] += a * wv.x; acc[i][1] += a * wv.y;
                acc[i][2] += a * wv.z; acc[i][3] += a * wv.w;
            }
        }
        #pragma unroll
        for (int i = 0; i < 4; ++i) {
            float4 o;
            o.x = ssp_f(acc[i][0]); o.y = ssp_f(acc[i][1]);
            o.z = ssp_f(acc[i][2]); o.w = ssp_f(acc[i][3]);
            *(float4*)&t_s[eb + i][c4] = o;
        }
    }
    __syncthreads();
    {
        const float4 bv = *(const float4*)(b2 + c4);
        #pragma unroll
        for (int i = 0; i < 4; ++i) { acc[i][0]=bv.x; acc[i][1]=bv.y; acc[i][2]=bv.z; acc[i][3]=bv.w; }
        #pragma unroll 4
        for (int k = 0; k < 128; ++k) {
            const float4 wv = *(const float4*)(w2 + k * 128 + c4);
            #pragma unroll
            for (int i = 0; i < 4; ++i) {
                const float a = t_s[eb + i][k];
                acc[i][0] += a * wv.x; acc[i][1] += a * wv.y;
                acc[i][2] += a * wv.z; acc[i][3] += a * wv.w;
            }
        }
    }
    #pragma unroll
    for (int i = 0; i < 4; ++i) {
        const int e = eb + i;
        if (e0 + e >= E) continue;
        const float Ce = C_s[e];
        const float4 xv = *(const float4*)(xh + (long)row_s[e] * 128 + c4);
        float* ag = agg + (long)col_s[e] * 128 + c4;
        atomicAdd(ag + 0, acc[i][0] * Ce * xv.x);
        atomicAdd(ag + 1, acc[i][1] * Ce * xv.y);
        atomicAdd(ag + 2, acc[i][2] * Ce * xv.z);
        atomicAdd(ag + 3, acc[i][3] * Ce * xv.w);
    }
}

// ---------------- readout ------------------------------------------------------
__global__ __launch_bounds__(128) void readout_simple(
    const float* __restrict__ h,
    const float* __restrict__ o1w, const float* __restrict__ o1b,
    const float* __restrict__ o2w, const float* __restrict__ o2b,
    const int* __restrict__ batch, float* __restrict__ accb)
{
    __shared__ float hr[128];
    __shared__ float vv[64];
    const int n = blockIdx.x;
    const int t = threadIdx.x;
    hr[t] = h[(long)n * 128 + t];
    __syncthreads();
    if (t < 64) {
        float a = o1b[t];
        #pragma unroll 8
        for (int k = 0; k < 128; ++k)
            a = fmaf(hr[k], o1w[k * 64 + t], a);
        vv[t] = ssp_f(a) * o2w[t];
    }
    __syncthreads();
    if (t < 32) vv[t] += vv[t + 32];
    __syncthreads();
    if (t < 16) vv[t] += vv[t + 16];
    __syncthreads();
    if (t < 8)  vv[t] += vv[t + 8];
    __syncthreads();
    if (t < 4)  vv[t] += vv[t + 4];
    __syncthreads();
    if (t < 2)  vv[t] += vv[t + 2];
    __syncthreads();
    if (t == 0) atomicAdd(&accb[batch[n]], vv[0] + vv[1] + o2b[0]);
}

// output is FLOAT32 (verified round 11)
__global__ void finalize_kernel(const float* __restrict__ accb,
                                float* __restrict__ out, int B)
{
    int t = blockIdx.x * 256 + threadIdx.x;
    if (t < B) out[t] = accb[t];
}

// ---------------- launch -------------------------------------------------------
extern "C" void kernel_launch(void* const* d_in, const int* in_sizes, int n_in,
                              void* d_out, int out_size, void* d_ws, size_t ws_size,
                              hipStream_t stream)
{
    const int N   = in_sizes[0];
    const int E   = in_sizes[3] / 2;
    const int B   = out_size;
    const int H   = 128;
    const int L   = in_sizes[7] / H;
    const int NB  = in_sizes[4] / E;
    const int F50 = in_sizes[6] / (L * H);
    const int NGS = F50 - NB;
    const float delta = 10.0f / (float)(NGS - 1);
    const float coeff = -0.5f / (delta * delta);

    const int fidx[16] = {1, 4, 5, 6, 7, 8, 9, 10, 11, 12, 13, 14, 15, 16, 17, 18};
    long foff[17]; foff[0] = 0;
    for (int i = 0; i < 16; ++i) foff[i + 1] = foff[i] + in_sizes[fidx[i]];

    float* F = (float*)d_ws;
    long base = (foff[16] + 3) & ~3L;
    float* h    = F + base;
    float* xh   = h + (long)N * H;
    float* agg  = xh + (long)N * H;
    float* accb = agg + (long)N * H;
    int*   flag  = (int*)(accb + ((B + 3) & ~3));
    int*   iflag = flag + 1;
    int*   zi     = flag + 4;
    int*   batchi = zi + N;
    int*   eidxi  = batchi + N;
    int*   count  = eidxi + 2 * E;
    int*   rowptr = count + N;
    int*   next   = rowptr + N + 1;
    int*   slot   = next + N;
    int*   perm   = slot + E;
    int*   rowS   = perm + E;
    int*   colS   = rowS + E;
    float* CS     = (float*)(colS + E);
    float* ewS    = CS + E;
    unsigned short* eaS = (unsigned short*)(ewS + E);      // 4E ushorts
    unsigned short* w1t = eaS + 4L * E;                    // L*128*64
    unsigned short* w2t = w1t + (long)L * 128 * 64;        // L*128*128
    long used_bytes = (long)((char*)(w2t + (long)L * 128 * 128) - (char*)d_ws);
    const bool use_fast = (used_bytes <= (long)ws_size) && (F50 <= 64) && (NB <= 4);

    sniff_kernel<<<1, 256, 0, stream>>>((const unsigned int*)d_in[5], flag);
    sniff_int_kernel<<<1, 128, 0, stream>>>((const unsigned int*)d_in[0], iflag);

    for (int i = 0; i < 16; ++i) {
        int n = in_sizes[fidx[i]];
        convert_kernel<<<(n + 255) / 256, 256, 0, stream>>>(d_in[fidx[i]], F + foff[i], n, flag);
    }
    convert_int_kernel<<<(N + 255) / 256, 256, 0, stream>>>(d_in[0], zi, N, iflag);
    convert_int_kernel<<<(N + 255) / 256, 256, 0, stream>>>(d_in[2], batchi, N, iflag);
    convert_int_kernel<<<(2 * E + 255) / 256, 256, 0, stream>>>(d_in[3], eidxi, 2 * E, iflag);

    const float* posf   = F + foff[0];
    const float* eattrf = F + foff[1];
    const float* embf   = F + foff[2];
    const float* w1   = F + foff[3];  const float* b1   = F + foff[4];
    const float* w2   = F + foff[5];  const float* b2   = F + foff[6];
    const float* cf1  = F + foff[7];  const float* cf2  = F + foff[8];
    const float* cf2b = F + foff[9];  const float* lin  = F + foff[10];
    const float* linb = F + foff[11]; const float* o1   = F + foff[12];
    const float* o1b  = F + foff[13]; const float* o2   = F + foff[14];
    const float* o2b  = F + foff[15];

    if (use_fast) {
        zero_int_kernel<<<(N + 255) / 256, 256, 0, stream>>>(count, N);
        hist_kernel<<<(E + 255) / 256, 256, 0, stream>>>(eidxi + E, count, E);
        scan_kernel<<<1, 256, 0, stream>>>(count, rowptr, next, N);
        slot_kernel<<<(E + 255) / 256, 256, 0, stream>>>(eidxi + E, next, slot, E);
        perm_kernel<<<(E + 255) / 256, 256, 0, stream>>>(slot, perm, E);
        prep_edges_kernel<<<(E + 255) / 256, 256, 0, stream>>>(
            posf, eidxi, eidxi + E, eattrf, perm, rowS, colS, CS, ewS, eaS, E, NB);
        for (int l = 0; l < L; ++l) {
            wtrans_kernel<<<(128 * 64 + 255) / 256, 256, 0, stream>>>(
                w1 + (long)l * F50 * H, w1t + (long)l * 128 * 64, F50, 64, 128);
            wtrans_kernel<<<(128 * 128 + 255) / 256, 256, 0, stream>>>(
                w2 + (long)l * H * H, w2t + (long)l * 128 * 128, 128, 128, 128);
        }
    }

    embed_kernel<<<(N * H + 255) / 256, 256, 0, stream>>>(zi, embf, h, N * H);
    hipMemsetAsync(accb, 0, (size_t)B * sizeof(float), stream);

    const int ngemm = (N + 31) / 32;
    const int nedge = (E + 31) / 32;
    for (int l = 0; l < L; ++l) {
        hipMemsetAsync(agg, 0, (size_t)N * H * sizeof(float), stream);
        node_gemm_tiled<0><<<ngemm, 256, 0, stream>>>(h, cf1 + (long)l * H * H, nullptr, xh, N);
        if (use_fast) {
            edge_mfma<<<nedge, 256, 0, stream>>>(
                rowS, colS, CS, ewS, eaS,
                w1t + (long)l * 128 * 64, b1 + (long)l * H,
                w2t + (long)l * 128 * 128, b2 + (long)l * H,
                xh, agg, E, NB, F50, delta, coeff);
        } else {
            edge_atomic<<<nedge, 256, 0, stream>>>(
                posf, eidxi, eidxi + E, eattrf,
                w1 + (long)l * F50 * H, b1 + (long)l * H,
                w2 + (long)l * H * H,  b2 + (long)l * H,
                xh, agg, E, NB, F50, delta, coeff);
        }
        node_gemm_tiled<1><<<ngemm, 256, 0, stream>>>(agg, cf2 + (long)l * H * H, cf2b + (long)l * H, xh, N);
        node_gemm_tiled<2><<<ngemm, 256, 0, stream>>>(xh, lin + (long)l * H * H, linb + (long)l * H, h, N);
    }

    readout_simple<<<N, 128, 0, stream>>>(h, o1, o1b, o2, o2b, batchi, accb);
    finalize_kernel<<<(B + 255) / 256, 256, 0, stream>>>(accb, (float*)d_out, B);
}

// Round 16
// 1530.801 us; speedup vs baseline: 2.8405x; 1.2148x over previous
//
#include <hip/hip_runtime.h>
#include <hip/hip_bf16.h>

typedef __attribute__((ext_vector_type(8))) short bfrag;
typedef __attribute__((ext_vector_type(4))) float f32x4;

// fast shifted softplus: __logf/__expf intrinsics (rel err ~2^-21, threshold 2.3e-2)
__device__ __forceinline__ float ssp_f(float x) {
    return fmaxf(x, 0.f) + __logf(1.f + __expf(-fabsf(x))) - 0.6931471805599453f;
}

__device__ __forceinline__ unsigned short f2b(float x) {
    __hip_bfloat16 h = __float2bfloat16(x);
    return *(unsigned short*)&h;
}

// ---------------- float dtype sniffer ----------------------------------------
__global__ void sniff_kernel(const unsigned int* __restrict__ raw, int* __restrict__ flag)
{
    __shared__ int cnt[256];
    const int t = threadIdx.x;
    unsigned int w = raw[t];
    unsigned int e = (w >> 7) & 0xFFu;
    cnt[t] = (e >= 100u && e <= 135u) ? 1 : 0;
    __syncthreads();
    for (int s = 128; s > 0; s >>= 1) {
        if (t < s) cnt[t] += cnt[t + s];
        __syncthreads();
    }
    if (t == 0) *flag = (cnt[0] >= 160) ? 1 : 0;   // 1 = floats are bf16
}

// ---------------- int width sniffer -------------------------------------------
__global__ void sniff_int_kernel(const unsigned int* __restrict__ z, int* __restrict__ iflag)
{
    __shared__ int cnt[128];
    const int t = threadIdx.x;
    cnt[t] = (z[2 * t + 1] == 0u) ? 1 : 0;
    __syncthreads();
    for (int s = 64; s > 0; s >>= 1) {
        if (t < s) cnt[t] += cnt[t + s];
        __syncthreads();
    }
    if (t == 0) *iflag = (cnt[0] >= 126) ? 1 : 0;  // 1 = ints are int64
}

// ---------------- converts -----------------------------------------------------
__global__ __launch_bounds__(256) void convert_kernel(
    const void* __restrict__ src, float* __restrict__ dst, int n,
    const int* __restrict__ flag)
{
    int i = blockIdx.x * 256 + threadIdx.x;
    if (i >= n) return;
    if (*flag) dst[i] = __bfloat162float(((const __hip_bfloat16*)src)[i]);
    else       dst[i] = ((const float*)src)[i];
}

__global__ __launch_bounds__(256) void convert_int_kernel(
    const void* __restrict__ src, int* __restrict__ dst, int n,
    const int* __restrict__ iflag)
{
    int i = blockIdx.x * 256 + threadIdx.x;
    if (i >= n) return;
    if (*iflag) dst[i] = (int)(((const long long*)src)[i]);
    else        dst[i] = ((const int*)src)[i];
}

// ---------------- node embedding gather ---------------------------------------
__global__ __launch_bounds__(256) void embed_kernel(
    const int* __restrict__ z, const float* __restrict__ embf,
    float* __restrict__ h, int NH)
{
    int idx = blockIdx.x * 256 + threadIdx.x;
    if (idx >= NH) return;
    h[idx] = embf[z[idx >> 7] * 128 + (idx & 127)];
}

// ---------------- CSR build ----------------------------------------------------
__global__ __launch_bounds__(256) void zero_int_kernel(int* p, int n)
{
    int i = blockIdx.x * 256 + threadIdx.x;
    if (i < n) p[i] = 0;
}

__global__ __launch_bounds__(256) void hist_kernel(const int* __restrict__ col,
                                                   int* __restrict__ count, int E)
{
    int e = blockIdx.x * 256 + threadIdx.x;
    if (e < E) atomicAdd(&count[col[e]], 1);
}

__global__ __launch_bounds__(256) void scan_kernel(const int* __restrict__ count,
                                                   int* __restrict__ rowptr,
                                                   int* __restrict__ next, int N)
{
    __shared__ int part[256];
    const int t = threadIdx.x;
    const int chunk = (N + 255) / 256;
    const int lo = t * chunk, hi = min(lo + chunk, N);
    int s = 0;
    for (int i = lo; i < hi; ++i) s += count[i];
    part[t] = s;
    __syncthreads();
    if (t == 0) {
        int run = 0;
        for (int i = 0; i < 256; ++i) { int v = part[i]; part[i] = run; run += v; }
        rowptr[N] = run;
    }
    __syncthreads();
    int run = part[t];
    for (int i = lo; i < hi; ++i) {
        rowptr[i] = run; next[i] = run;
        run += count[i];
    }
}

__global__ __launch_bounds__(256) void slot_kernel(const int* __restrict__ col,
                                                   int* __restrict__ next,
                                                   int* __restrict__ slot, int E)
{
    int e = blockIdx.x * 256 + threadIdx.x;
    if (e < E) slot[e] = atomicAdd(&next[col[e]], 1);
}

__global__ __launch_bounds__(256) void perm_kernel(const int* __restrict__ slot,
                                                   int* __restrict__ perm, int E)
{
    int e = blockIdx.x * 256 + threadIdx.x;
    if (e < E) perm[slot[e]] = e;
}

// ---------------- pre-permute edge data into sorted order ---------------------
__global__ __launch_bounds__(256) void prep_edges_kernel(
    const float* __restrict__ posf, const int* __restrict__ row,
    const int* __restrict__ col, const float* __restrict__ eattrf,
    const int* __restrict__ perm,
    int* __restrict__ rowS, int* __restrict__ colS,
    float* __restrict__ CS, float* __restrict__ ewS,
    unsigned short* __restrict__ eaS, int E, int NB)
{
    int p = blockIdx.x * 256 + threadIdx.x;
    if (p >= E) return;
    const int e = perm[p];
    const int r = row[e], c = col[e];
    float dx = posf[r*3+0] - posf[c*3+0];
    float dy = posf[r*3+1] - posf[c*3+1];
    float dz = posf[r*3+2] - posf[c*3+2];
    float ew = sqrtf(dx*dx + dy*dy + dz*dz);
    rowS[p] = r; colS[p] = c; ewS[p] = ew;
    CS[p] = 0.5f * (cosf(ew * 0.3141592653589793f) + 1.0f);
    unsigned short* o = eaS + (long)p * 4;
    for (int q = 0; q < 4; ++q)
        o[q] = (q < NB) ? f2b(eattrf[(long)e * NB + q]) : (unsigned short)0;
}

// ---------------- weight transpose to bf16 N-major ----------------------------
__global__ __launch_bounds__(256) void wtrans_kernel(
    const float* __restrict__ src, unsigned short* __restrict__ dst,
    int K, int Kpad, int N)
{
    int idx = blockIdx.x * 256 + threadIdx.x;
    if (idx >= N * Kpad) return;
    int n = idx / Kpad, k = idx - n * Kpad;
    dst[idx] = (k < K) ? f2b(src[k * N + n]) : (unsigned short)0;
}

// ---------------- tiled node GEMM [N,128]@[128,128] (fp32) --------------------
template<int MODE>
__global__ __launch_bounds__(256) void node_gemm_tiled(
    const float* __restrict__ in, const float* __restrict__ W,
    const float* __restrict__ bias, float* __restrict__ out, int N)
{
    __shared__ float in_s[32][128];
    const int t = threadIdx.x;
    const long n0 = (long)blockIdx.x * 32;
    for (int i = t; i < 32 * 128; i += 256) {
        long n = n0 + (i >> 7);
        in_s[i >> 7][i & 127] = (n < N) ? in[n * 128 + (i & 127)] : 0.f;
    }
    __syncthreads();
    const int j = t & 31, sub = t >> 5;
    const int c4 = j * 4, rb = sub * 4;
    float acc[4][4];
    float4 bv = make_float4(0.f, 0.f, 0.f, 0.f);
    if (MODE != 0) bv = *(const float4*)(bias + c4);
    #pragma unroll
    for (int i = 0; i < 4; ++i) { acc[i][0]=bv.x; acc[i][1]=bv.y; acc[i][2]=bv.z; acc[i][3]=bv.w; }
    #pragma unroll 4
    for (int k = 0; k < 128; ++k) {
        const float4 wv = *(const float4*)(W + k * 128 + c4);
        #pragma unroll
        for (int i = 0; i < 4; ++i) {
            const float a = in_s[rb + i][k];
            acc[i][0] += a * wv.x; acc[i][1] += a * wv.y;
            acc[i][2] += a * wv.z; acc[i][3] += a * wv.w;
        }
    }
    #pragma unroll
    for (int i = 0; i < 4; ++i) {
        long n = n0 + rb + i;
        if (n >= N) continue;
        float4 o;
        if (MODE == 1) {
            o.x = ssp_f(acc[i][0]); o.y = ssp_f(acc[i][1]);
            o.z = ssp_f(acc[i][2]); o.w = ssp_f(acc[i][3]);
        } else {
            o.x = acc[i][0]; o.y = acc[i][1]; o.z = acc[i][2]; o.w = acc[i][3];
        }
        if (MODE == 2) {
            float4 p = *(const float4*)(out + n * 128 + c4);
            o.x += p.x; o.y += p.y; o.z += p.z; o.w += p.w;
        }
        *(float4*)(out + n * 128 + c4) = o;
    }
}

// ---------------- MFMA edge kernel (sorted order) -----------------------------
// 32 edges/block, 4 waves, bf16 MFMA 16x16x32. Epilogue: each (edge,col) owned
// by exactly one thread -> plain padded-LDS store (no atomics), then per-run
// column reduction -> one global atomic per run per column.
__global__ __launch_bounds__(256) void edge_mfma(
    const int* __restrict__ rowS, const int* __restrict__ colS,
    const float* __restrict__ CS, const float* __restrict__ ewS,
    const unsigned short* __restrict__ eaS,
    const unsigned short* __restrict__ w1t, const float* __restrict__ b1,
    const unsigned short* __restrict__ w2t, const float* __restrict__ b2,
    const float* __restrict__ xh, float* __restrict__ agg,
    int E, int NB, int F50, float delta, float coeff)
{
    __shared__ __align__(16) short ea_b[32][64];   // bf16, K-padded to 64
    __shared__ __align__(16) short t_b[32][128];   // bf16 GEMM1 output
    __shared__ float runbuf[32][136];              // +8 pad: quads hit disjoint bank octets
    __shared__ int   row_s[32];
    __shared__ int   col_s[32];
    __shared__ float C_s[32];
    __shared__ float ew_s[32];
    __shared__ int   runcol_s[32];
    __shared__ int   runstart_s[33];
    __shared__ int   nruns_s;

    const int t = threadIdx.x;
    const long p0 = (long)blockIdx.x * 32;

    if (t < 32) {
        long p = p0 + t; if (p >= E) p = E - 1;
        row_s[t] = rowS[p];
        col_s[t] = colS[p];
        C_s[t]   = (p0 + t < E) ? CS[p] : 0.f;
        ew_s[t]  = ewS[p];
    }
    __syncthreads();
    if (t == 0) {
        int nr = 0;
        for (int i = 0; i < 32; ++i) {
            if (i == 0 || col_s[i] != col_s[i - 1]) {
                runcol_s[nr] = col_s[i];
                runstart_s[nr] = i;
                ++nr;
            }
        }
        runstart_s[nr] = 32;
        nruns_s = nr;
    }
    // fill ea_b (bf16): [0,NB) from eaS, [NB,F50) gaussians, rest zero
    for (int i = t; i < 32 * 64; i += 256) {
        const int e = i >> 6, k = i & 63;
        long p = p0 + e; if (p >= E) p = E - 1;
        unsigned short v;
        if (k < NB)        v = eaS[p * 4 + k];
        else if (k < F50) {
            float d = ew_s[e] - (float)(k - NB) * delta;
            v = f2b(__expf(coeff * d * d));
        } else             v = 0;
        ea_b[e][k] = (short)v;
    }
    __syncthreads();

    const int lane = t & 63;
    const int w    = t >> 6;
    const int colL = lane & 15;
    const int quad = lane >> 4;
    const int m0   = (w & 1) * 16;

    // ---- GEMM1: ea[32x64pad] @ w1t -> ssp -> t_b (bf16) ----
    {
        f32x4 acc[4];
        #pragma unroll
        for (int tt = 0; tt < 4; ++tt) acc[tt] = (f32x4){0.f, 0.f, 0.f, 0.f};
        #pragma unroll
        for (int ks = 0; ks < 2; ++ks) {
            const bfrag a = *(const bfrag*)&ea_b[m0 + colL][ks * 32 + quad * 8];
            #pragma unroll
            for (int tt = 0; tt < 4; ++tt) {
                const int n0 = ((w >> 1) * 4 + tt) * 16;
                const bfrag b = *(const bfrag*)&w1t[(long)(n0 + colL) * 64 + ks * 32 + quad * 8];
                acc[tt] = __builtin_amdgcn_mfma_f32_16x16x32_bf16(a, b, acc[tt], 0, 0, 0);
            }
        }
        #pragma unroll
        for (int tt = 0; tt < 4; ++tt) {
            const int n0 = ((w >> 1) * 4 + tt) * 16;
            const float bcol = b1[n0 + colL];
            #pragma unroll
            for (int reg = 0; reg < 4; ++reg) {
                float v = ssp_f(acc[tt][reg] + bcol);
                t_b[m0 + quad * 4 + reg][n0 + colL] = (short)f2b(v);
            }
        }
    }
    __syncthreads();

    // ---- GEMM2: t_b[32x128] @ w2t; store msg directly to runbuf ----
    {
        f32x4 acc[4];
        #pragma unroll
        for (int tt = 0; tt < 4; ++tt) acc[tt] = (f32x4){0.f, 0.f, 0.f, 0.f};
        #pragma unroll
        for (int ks = 0; ks < 4; ++ks) {
            const bfrag a = *(const bfrag*)&t_b[m0 + colL][ks * 32 + quad * 8];
            #pragma unroll
            for (int tt = 0; tt < 4; ++tt) {
                const int n0 = ((w >> 1) * 4 + tt) * 16;
                const bfrag b = *(const bfrag*)&w2t[(long)(n0 + colL) * 128 + ks * 32 + quad * 8];
                acc[tt] = __builtin_amdgcn_mfma_f32_16x16x32_bf16(a, b, acc[tt], 0, 0, 0);
            }
        }
        const int ebase = m0 + quad * 4;
        #pragma unroll
        for (int tt = 0; tt < 4; ++tt) {
            const int n0 = ((w >> 1) * 4 + tt) * 16;
            const int cg = n0 + colL;
            const float bcol = b2[cg];
            #pragma unroll
            for (int reg = 0; reg < 4; ++reg) {
                const int e = ebase + reg;
                const float v = acc[tt][reg] + bcol;
                runbuf[e][cg] = v * C_s[e] * xh[(long)row_s[e] * 128 + cg];
            }
        }
    }
    __syncthreads();

    // ---- per-run column reduction -> global atomic ----
    const int nr = nruns_s;
    const int cc = t & 127;
    for (int r = t >> 7; r < nr; r += 2) {
        float a = 0.f;
        const int s1 = runstart_s[r + 1];
        for (int e = runstart_s[r]; e < s1; ++e)
            a += runbuf[e][cc];
        atomicAdd(&agg[(long)runcol_s[r] * 128 + cc], a);
    }
}

// ---------------- fp32 atomic edge kernel (fallback) --------------------------
__global__ __launch_bounds__(256) void edge_atomic(
    const float* __restrict__ posf,
    const int* __restrict__ row, const int* __restrict__ col,
    const float* __restrict__ eattrf,
    const float* __restrict__ w1, const float* __restrict__ b1,
    const float* __restrict__ w2, const float* __restrict__ b2,
    const float* __restrict__ xh, float* __restrict__ agg,
    int E, int NB, int F50, float delta, float coeff)
{
    __shared__ float ea_s[32][52];
    __shared__ float t_s[32][128];
    __shared__ int   row_s[32];
    __shared__ int   col_s[32];
    __shared__ float C_s[32];
    __shared__ float ew_s[32];

    const int t = threadIdx.x;
    const long e0 = (long)blockIdx.x * 32;

    if (t < 32) {
        long e = e0 + t; if (e >= E) e = E - 1;
        const int r = row[e], c = col[e];
        row_s[t] = r; col_s[t] = c;
        float dx = posf[r*3+0] - posf[c*3+0];
        float dy = posf[r*3+1] - posf[c*3+1];
        float dz = posf[r*3+2] - posf[c*3+2];
        float ew = sqrtf(dx*dx + dy*dy + dz*dz);
        ew_s[t] = ew;
        C_s[t]  = (e0 + t < E) ? 0.5f * (cosf(ew * 0.3141592653589793f) + 1.0f) : 0.f;
        for (int q = 0; q < NB; ++q)
            ea_s[t][q] = eattrf[e * NB + q];
    }
    __syncthreads();
    {
        const int NGS = F50 - NB;
        for (int i = t; i < 32 * NGS; i += 256) {
            const int e = i / NGS, g = i - e * NGS;
            const float d = ew_s[e] - (float)g * delta;
            ea_s[e][NB + g] = __expf(coeff * d * d);
        }
    }
    __syncthreads();

    const int j = t & 31, sub = t >> 5;
    const int c4 = j * 4, eb = sub * 4;
    float acc[4][4];
    {
        const float4 bv = *(const float4*)(b1 + c4);
        #pragma unroll
        for (int i = 0; i < 4; ++i) { acc[i][0]=bv.x; acc[i][1]=bv.y; acc[i][2]=bv.z; acc[i][3]=bv.w; }
        for (int k = 0; k < F50; ++k) {
            const float4 wv = *(const float4*)(w1 + k * 128 + c4);
            #pragma unroll
            for (int i = 0; i < 4; ++i) {
                const float a = ea_s[eb + i][k];
                acc[i][0] += a * wv.x; acc[i][1] += a * wv.y;
                acc[i][2] += a * wv.z; acc[i][3] += a * wv.w;
            }
        }
        #pragma unroll
        for (int i = 0; i < 4; ++i) {
            float4 o;
            o.x = ssp_f(acc[i][0]); o.y = ssp_f(acc[i][1]);
            o.z = ssp_f(acc[i][2]); o.w = ssp_f(acc[i][3]);
            *(float4*)&t_s[eb + i][c4] = o;
        }
    }
    __syncthreads();
    {
        const float4 bv = *(const float4*)(b2 + c4);
        #pragma unroll
        for (int i = 0; i < 4; ++i) { acc[i][0]=bv.x; acc[i][1]=bv.y; acc[i][2]=bv.z; acc[i][3]=bv.w; }
        #pragma unroll 4
        for (int k = 0; k < 128; ++k) {
            const float4 wv = *(const float4*)(w2 + k * 128 + c4);
            #pragma unroll
            for (int i = 0; i < 4; ++i) {
                const float a = t_s[eb + i][k];
                acc[i][0] += a * wv.x; acc[i][1] += a * wv.y;
                acc[i][2] += a * wv.z; acc[i][3] += a * wv.w;
            }
        }
    }
    #pragma unroll
    for (int i = 0; i < 4; ++i) {
        const int e = eb + i;
        if (e0 + e >= E) continue;
        const float Ce = C_s[e];
        const float4 xv = *(const float4*)(xh + (long)row_s[e] * 128 + c4);
        float* ag = agg + (long)col_s[e] * 128 + c4;
        atomicAdd(ag + 0, acc[i][0] * Ce * xv.x);
        atomicAdd(ag + 1, acc[i][1] * Ce * xv.y);
        atomicAdd(ag + 2, acc[i][2] * Ce * xv.z);
        atomicAdd(ag + 3, acc[i][3] * Ce * xv.w);
    }
}

// ---------------- readout ------------------------------------------------------
__global__ __launch_bounds__(128) void readout_simple(
    const float* __restrict__ h,
    const float* __restrict__ o1w, const float* __restrict__ o1b,
    const float* __restrict__ o2w, const float* __restrict__ o2b,
    const int* __restrict__ batch, float* __restrict__ accb)
{
    __shared__ float hr[128];
    __shared__ float vv[64];
    const int n = blockIdx.x;
    const int t = threadIdx.x;
    hr[t] = h[(long)n * 128 + t];
    __syncthreads();
    if (t < 64) {
        float a = o1b[t];
        #pragma unroll 8
        for (int k = 0; k < 128; ++k)
            a = fmaf(hr[k], o1w[k * 64 + t], a);
        vv[t] = ssp_f(a) * o2w[t];
    }
    __syncthreads();
    if (t < 32) vv[t] += vv[t + 32];
    __syncthreads();
    if (t < 16) vv[t] += vv[t + 16];
    __syncthreads();
    if (t < 8)  vv[t] += vv[t + 8];
    __syncthreads();
    if (t < 4)  vv[t] += vv[t + 4];
    __syncthreads();
    if (t < 2)  vv[t] += vv[t + 2];
    __syncthreads();
    if (t == 0) atomicAdd(&accb[batch[n]], vv[0] + vv[1] + o2b[0]);
}

// output is FLOAT32 (verified round 11)
__global__ void finalize_kernel(const float* __restrict__ accb,
                                float* __restrict__ out, int B)
{
    int t = blockIdx.x * 256 + threadIdx.x;
    if (t < B) out[t] = accb[t];
}

// ---------------- launch -------------------------------------------------------
extern "C" void kernel_launch(void* const* d_in, const int* in_sizes, int n_in,
                              void* d_out, int out_size, void* d_ws, size_t ws_size,
                              hipStream_t stream)
{
    const int N   = in_sizes[0];
    const int E   = in_sizes[3] / 2;
    const int B   = out_size;
    const int H   = 128;
    const int L   = in_sizes[7] / H;
    const int NB  = in_sizes[4] / E;
    const int F50 = in_sizes[6] / (L * H);
    const int NGS = F50 - NB;
    const float delta = 10.0f / (float)(NGS - 1);
    const float coeff = -0.5f / (delta * delta);

    const int fidx[16] = {1, 4, 5, 6, 7, 8, 9, 10, 11, 12, 13, 14, 15, 16, 17, 18};
    long foff[17]; foff[0] = 0;
    for (int i = 0; i < 16; ++i) foff[i + 1] = foff[i] + in_sizes[fidx[i]];

    float* F = (float*)d_ws;
    long base = (foff[16] + 3) & ~3L;
    float* h    = F + base;
    float* xh   = h + (long)N * H;
    float* agg  = xh + (long)N * H;
    float* accb = agg + (long)N * H;
    int*   flag  = (int*)(accb + ((B + 3) & ~3));
    int*   iflag = flag + 1;
    int*   zi     = flag + 4;
    int*   batchi = zi + N;
    int*   eidxi  = batchi + N;
    int*   count  = eidxi + 2 * E;
    int*   rowptr = count + N;
    int*   next   = rowptr + N + 1;
    int*   slot   = next + N;
    int*   perm   = slot + E;
    int*   rowS   = perm + E;
    int*   colS   = rowS + E;
    float* CS     = (float*)(colS + E);
    float* ewS    = CS + E;
    unsigned short* eaS = (unsigned short*)(ewS + E);      // 4E ushorts
    unsigned short* w1t = eaS + 4L * E;                    // L*128*64
    unsigned short* w2t = w1t + (long)L * 128 * 64;        // L*128*128
    long used_bytes = (long)((char*)(w2t + (long)L * 128 * 128) - (char*)d_ws);
    const bool use_fast = (used_bytes <= (long)ws_size) && (F50 <= 64) && (NB <= 4);

    sniff_kernel<<<1, 256, 0, stream>>>((const unsigned int*)d_in[5], flag);
    sniff_int_kernel<<<1, 128, 0, stream>>>((const unsigned int*)d_in[0], iflag);

    for (int i = 0; i < 16; ++i) {
        int n = in_sizes[fidx[i]];
        convert_kernel<<<(n + 255) / 256, 256, 0, stream>>>(d_in[fidx[i]], F + foff[i], n, flag);
    }
    convert_int_kernel<<<(N + 255) / 256, 256, 0, stream>>>(d_in[0], zi, N, iflag);
    convert_int_kernel<<<(N + 255) / 256, 256, 0, stream>>>(d_in[2], batchi, N, iflag);
    convert_int_kernel<<<(2 * E + 255) / 256, 256, 0, stream>>>(d_in[3], eidxi, 2 * E, iflag);

    const float* posf   = F + foff[0];
    const float* eattrf = F + foff[1];
    const float* embf   = F + foff[2];
    const float* w1   = F + foff[3];  const float* b1   = F + foff[4];
    const float* w2   = F + foff[5];  const float* b2   = F + foff[6];
    const float* cf1  = F + foff[7];  const float* cf2  = F + foff[8];
    const float* cf2b = F + foff[9];  const float* lin  = F + foff[10];
    const float* linb = F + foff[11]; const float* o1   = F + foff[12];
    const float* o1b  = F + foff[13]; const float* o2   = F + foff[14];
    const float* o2b  = F + foff[15];

    if (use_fast) {
        zero_int_kernel<<<(N + 255) / 256, 256, 0, stream>>>(count, N);
        hist_kernel<<<(E + 255) / 256, 256, 0, stream>>>(eidxi + E, count, E);
        scan_kernel<<<1, 256, 0, stream>>>(count, rowptr, next, N);
        slot_kernel<<<(E + 255) / 256, 256, 0, stream>>>(eidxi + E, next, slot, E);
        perm_kernel<<<(E + 255) / 256, 256, 0, stream>>>(slot, perm, E);
        prep_edges_kernel<<<(E + 255) / 256, 256, 0, stream>>>(
            posf, eidxi, eidxi + E, eattrf, perm, rowS, colS, CS, ewS, eaS, E, NB);
        for (int l = 0; l < L; ++l) {
            wtrans_kernel<<<(128 * 64 + 255) / 256, 256, 0, stream>>>(
                w1 + (long)l * F50 * H, w1t + (long)l * 128 * 64, F50, 64, 128);
            wtrans_kernel<<<(128 * 128 + 255) / 256, 256, 0, stream>>>(
                w2 + (long)l * H * H, w2t + (long)l * 128 * 128, 128, 128, 128);
        }
    }

    embed_kernel<<<(N * H + 255) / 256, 256, 0, stream>>>(zi, embf, h, N * H);
    hipMemsetAsync(accb, 0, (size_t)B * sizeof(float), stream);

    const int ngemm = (N + 31) / 32;
    const int nedge = (E + 31) / 32;
    for (int l = 0; l < L; ++l) {
        hipMemsetAsync(agg, 0, (size_t)N * H * sizeof(float), stream);
        node_gemm_tiled<0><<<ngemm, 256, 0, stream>>>(h, cf1 + (long)l * H * H, nullptr, xh, N);
        if (use_fast) {
            edge_mfma<<<nedge, 256, 0, stream>>>(
                rowS, colS, CS, ewS, eaS,
                w1t + (long)l * 128 * 64, b1 + (long)l * H,
                w2t + (long)l * 128 * 128, b2 + (long)l * H,
                xh, agg, E, NB, F50, delta, coeff);
        } else {
            edge_atomic<<<nedge, 256, 0, stream>>>(
                posf, eidxi, eidxi + E, eattrf,
                w1 + (long)l * F50 * H, b1 + (long)l * H,
                w2 + (long)l * H * H,  b2 + (long)l * H,
                xh, agg, E, NB, F50, delta, coeff);
        }
        node_gemm_tiled<1><<<ngemm, 256, 0, stream>>>(agg, cf2 + (long)l * H * H, cf2b + (long)l * H, xh, N);
        node_gemm_tiled<2><<<ngemm, 256, 0, stream>>>(xh, lin + (long)l * H * H, linb + (long)l * H, h, N);
    }

    readout_simple<<<N, 128, 0, stream>>>(h, o1, o1b, o2, o2b, batchi, accb);
    finalize_kernel<<<(B + 255) / 256, 256, 0, stream>>>(accb, (float*)d_out, B);
}